// Round 11
// baseline (177.464 us; speedup 1.0000x reference)
//
#include <hip/hip_runtime.h>
#include <cstdint>
#include <cstddef>

#define HW_N   262144       // 512*512 elements per (b,c) map
#define ROWS   128          // 32*4 maps
#define POS_STRIDE 196608   // per-row slab for compacted positives (k ~ 131072 +- ~700)
#define NCHUNK 512          // 512-elem chunks per row (one wave-shot each)

// fast log(1 + exp(-|z|)): arg of log in [1,2] -> v_exp + v_log, abs err ~1e-7
__device__ __forceinline__ float lg_term(float z) {
    return __logf(1.0f + __expf(-fabsf(z)));
}

__device__ __forceinline__ void block_reduce_add(double v, double* target, int tid) {
    #pragma unroll
    for (int o = 32; o > 0; o >>= 1) v += __shfl_down(v, o);
    __shared__ double sred[16];
    const int lane = tid & 63, wave = tid >> 6;
    if (lane == 0) sred[wave] = v;
    __syncthreads();
    if (tid == 0) {
        double s = 0.0;
        const int nw = blockDim.x >> 6;
        for (int w = 0; w < nw; ++w) s += sred[w];
        atomicAdd(target, s);
    }
}

// ---- pass 1: t -> bitmask + per-512-chunk positive counts (no barriers) ----
__global__ __launch_bounds__(1024) void count_kernel(
        const int4* __restrict__ t4, unsigned char* __restrict__ mask,
        int* __restrict__ chunkcnt) {
    const int blk = blockIdx.x;                 // 1024 blocks, 32768 elems each
    const size_t e0 = (size_t)blk * 32768;
    const int tid = threadIdx.x;
    const int lane = tid & 63, wave = tid >> 6; // 16 waves
    #pragma unroll
    for (int it = 0; it < 4; ++it) {
        const int j8 = it * 1024 + tid;         // 8-elem group within block
        const int4 a = t4[e0 / 4 + 2 * j8];
        const int4 b = t4[e0 / 4 + 2 * j8 + 1];
        const unsigned m =
            (unsigned)(a.x > 0)        | ((unsigned)(a.y > 0) << 1) |
            ((unsigned)(a.z > 0) << 2) | ((unsigned)(a.w > 0) << 3) |
            ((unsigned)(b.x > 0) << 4) | ((unsigned)(b.y > 0) << 5) |
            ((unsigned)(b.z > 0) << 6) | ((unsigned)(b.w > 0) << 7);
        mask[e0 / 8 + j8] = (unsigned char)m;
        int c = __popc(m);
        #pragma unroll
        for (int o = 32; o > 0; o >>= 1) c += __shfl_down(c, o);
        if (lane == 0) chunkcnt[blk * 64 + it * 16 + wave] = c;  // chunk = elem/512
    }
}

// ---- pass 2: per-row exclusive scan of 512 chunk counts -> chunkoff, k ----
__global__ __launch_bounds__(512) void offsets_kernel(
        const int* __restrict__ chunkcnt, int* __restrict__ chunkoff,
        int* __restrict__ kArr, double* __restrict__ acc) {
    const int row = blockIdx.x;
    const int tid = threadIdx.x;
    const int lane = tid & 63, wave = tid >> 6;   // 8 waves
    const int c = chunkcnt[row * NCHUNK + tid];
    int incl = c;
    #pragma unroll
    for (int o = 1; o < 64; o <<= 1) {
        const int u = __shfl_up(incl, o);
        if (lane >= o) incl += u;
    }
    __shared__ int wt[8];
    if (lane == 63) wt[wave] = incl;
    __syncthreads();
    int wpre = 0;
    #pragma unroll
    for (int w = 0; w < 8; ++w) wpre += (w < wave) ? wt[w] : 0;
    chunkoff[row * NCHUNK + tid] = wpre + incl - c;
    if (tid == NCHUNK - 1) {
        int k = wpre + incl;
        k = k < 1 ? 1 : k;
        kArr[row] = k < POS_STRIDE ? k : POS_STRIDE;
    }
    if (blockIdx.x == 0 && tid < 2) acc[tid] = 0.0;
}

// ---- pass 3: barrier-free compaction (wave-local ballots) + fused CE loss ----
__global__ __launch_bounds__(256) void compact_kernel(
        const float4* __restrict__ x4, const unsigned char* __restrict__ mask,
        const int* __restrict__ chunkoff, float* __restrict__ pos,
        double* __restrict__ acc) {
    const int blk  = blockIdx.x;            // 4096 blocks, 8192 elems each
    const int row  = blk >> 5;              // 32 blocks/row
    const int bpart = blk & 31;
    const float4* xr = x4 + (size_t)row * (HW_N / 4);
    const unsigned char* mr = mask + (size_t)row * (HW_N / 8);
    float* pr = pos + (size_t)row * POS_STRIDE;
    const int* cor = chunkoff + row * NCHUNK;

    const int tid  = threadIdx.x;
    const int lane = tid & 63;
    const int wave = tid >> 6;              // 0..3
    const unsigned long long below = (1ull << lane) - 1ull;

    double dce = 0.0;
    #pragma unroll
    for (int i = 0; i < 4; ++i) {
        const int rc = bpart * 16 + i * 4 + wave;   // row-chunk id (0..511)
        const int j0 = rc * 512 + lane * 8;          // element within row
        const float4 a = xr[j0 / 4];
        const float4 b = xr[j0 / 4 + 1];
        const unsigned mb = mr[j0 >> 3];
        int rank = 0;
        #pragma unroll
        for (int s = 0; s < 8; ++s) {
            const unsigned long long bs = __ballot((mb >> s) & 1);
            rank += __popcll(bs & below);
        }
        int r = cor[rc] + rank;
        const float vv0 = a.x, vv1 = a.y, vv2 = a.z, vv3 = a.w;
        const float vv4 = b.x, vv5 = b.y, vv6 = b.z, vv7 = b.w;
        #define WR(s, v) if ((mb >> s) & 1) { if (r < POS_STRIDE) pr[r] = v; ++r; }
        WR(0, vv0) WR(1, vv1) WR(2, vv2) WR(3, vv3)
        WR(4, vv4) WR(5, vv5) WR(6, vv6) WR(7, vv7)
        #undef WR
        float sce = 0.0f;
        #define CE(s, v) sce += (((mb >> s) & 1) ? fmaxf(-(v), 0.0f) : fmaxf(v, 0.0f)) + lg_term(v);
        CE(0, vv0) CE(1, vv1) CE(2, vv2) CE(3, vv3)
        CE(4, vv4) CE(5, vv5) CE(6, vv6) CE(7, vv7)
        #undef CE
        dce += (double)sce;
    }
    block_reduce_add(dce, &acc[1], tid);
}

// ---- pass 4: m-centric sim loss: each pos[m] serves j = m + i*k (coalesced streams) ----
__global__ __launch_bounds__(256) void loss_kernel(
        const float* __restrict__ x, const unsigned char* __restrict__ mask,
        const float* __restrict__ pos, const int* __restrict__ kArr,
        double* __restrict__ acc) {
    const int blk  = blockIdx.x;
    const int row  = blk >> 5;              // 32 blocks/row
    const int part = blk & 31;
    const int k = kArr[row];
    const float* xr = x + (size_t)row * HW_N;
    const unsigned char* mr = mask + (size_t)row * (HW_N / 8);
    const float* pr = pos + (size_t)row * POS_STRIDE;

    const int c0  = HW_N / k;               // base copy count (>= 1)
    const int rem = HW_N - c0 * k;          // m < rem gets one extra copy
    int ms = (k + 31) / 32;
    ms = (ms + 3) & ~3;                     // multiple of 4 -> aligned float4 pos loads
    const int mstart = part * ms;
    const int mend   = (mstart + ms < k) ? (mstart + ms) : k;

    const int tid = threadIdx.x;
    double dab = 0.0;

    for (int m4 = mstart + tid * 4; m4 < mend; m4 += 256 * 4) {
        float sab = 0.0f;
        if (m4 + 4 <= mend) {
            const float4 pv = *reinterpret_cast<const float4*>(pr + m4);
            const float v0 = pv.x, v1 = pv.y, v2 = pv.z, v3 = pv.w;
            // base copies i = 0..c0-1: j = m + i*k (sequential streams)
            for (int i = 0; i < c0; ++i) {
                const int jb = m4 + i * k;
                const unsigned bits =
                    ((unsigned)mr[jb >> 3] | ((unsigned)mr[(jb >> 3) + 1] << 8)) >> (jb & 7);
                #define AT(e, v) { \
                    const float dx = (v) * xr[jb + e]; \
                    sab += (((bits >> e) & 1) ? fmaxf(-dx, 0.0f) : fmaxf(dx, 0.0f)) + lg_term(dx); }
                AT(0, v0) AT(1, v1) AT(2, v2) AT(3, v3)
                #undef AT
            }
            // extra copy for m < rem
            int nex = rem - m4;
            nex = nex < 0 ? 0 : (nex > 4 ? 4 : nex);
            if (nex > 0) {
                const int jb = m4 + c0 * k;
                const unsigned bits =
                    ((unsigned)mr[jb >> 3] | ((unsigned)mr[(jb >> 3) + 1] << 8)) >> (jb & 7);
                #pragma unroll
                for (int e = 0; e < 4; ++e) {
                    if (e < nex) {
                        const float v = (e == 0) ? v0 : (e == 1) ? v1 : (e == 2) ? v2 : v3;
                        const float dx = v * xr[jb + e];
                        sab += (((bits >> e) & 1) ? fmaxf(-dx, 0.0f) : fmaxf(dx, 0.0f)) + lg_term(dx);
                    }
                }
            }
            // B terms, weighted by copy count
            #define BT(e, v) { \
                const float wgt = (float)c0 + (((m4 + e) < rem) ? 1.0f : 0.0f); \
                sab += wgt * (fmaxf(-(v), 0.0f) + lg_term(v)); }
            BT(0, v0) BT(1, v1) BT(2, v2) BT(3, v3)
            #undef BT
        } else {
            // ragged tail (last iteration of last block of a row)
            for (int m = m4; m < mend; ++m) {
                const float v = pr[m];
                const int copies = c0 + (m < rem ? 1 : 0);
                for (int i = 0; i < copies; ++i) {
                    const int j = m + i * k;
                    const float dx = v * xr[j];
                    const int tt = (mr[j >> 3] >> (j & 7)) & 1;
                    sab += (tt ? fmaxf(-dx, 0.0f) : fmaxf(dx, 0.0f)) + lg_term(dx);
                }
                sab += (float)copies * (fmaxf(-v, 0.0f) + lg_term(v));
            }
        }
        dab += (double)sab;
    }
    block_reduce_add(dab, &acc[0], tid);
}

__global__ void finalize_kernel(const double* __restrict__ acc, float* __restrict__ out) {
    if (threadIdx.x == 0 && blockIdx.x == 0) {
        const double inv = 1.0 / 33554432.0;    // 1 / (ROWS * HW_N)
        out[0] = (float)(0.5 * acc[0] * inv + 0.5 * acc[1] * inv);  // ALPHA = 0.5
    }
}

extern "C" void kernel_launch(void* const* d_in, const int* in_sizes, int n_in,
                              void* d_out, int out_size, void* d_ws, size_t ws_size,
                              hipStream_t stream) {
    const float* x = (const float*)d_in[0];
    const int*   t = (const int*)d_in[1];
    float* out = (float*)d_out;

    // workspace layout (max used ~117 MB; R1-R8 proved >= ~135 MB available):
    //   [0,16)           two f64 accumulators (0: sim A+B, 1: CE)
    //   [16384,16896)    kArr      (ROWS ints)
    //   [32768, +4MB)    mask      (ROWS*HW_N/8 bytes)
    //   [8MB, +256KB)    chunkcnt  (ROWS*NCHUNK ints)
    //   [12MB, +256KB)   chunkoff  (ROWS*NCHUNK ints)
    //   [16MB, +100.7MB) pos       (ROWS*POS_STRIDE floats)
    double*        acc      = (double*)d_ws;
    int*           kArr     = (int*)((char*)d_ws + 16384);
    unsigned char* mask     = (unsigned char*)d_ws + 32768;
    int*           chunkcnt = (int*)((char*)d_ws + (8u << 20));
    int*           chunkoff = (int*)((char*)d_ws + (12u << 20));
    float*         pos      = (float*)((char*)d_ws + (16u << 20));

    count_kernel   <<<1024, 1024, 0, stream>>>((const int4*)t, mask, chunkcnt);
    offsets_kernel <<<ROWS, 512, 0, stream>>>(chunkcnt, chunkoff, kArr, acc);
    compact_kernel <<<ROWS * 32, 256, 0, stream>>>((const float4*)x, mask, chunkoff, pos, acc);
    loss_kernel    <<<ROWS * 32, 256, 0, stream>>>(x, mask, pos, kArr, acc);
    finalize_kernel<<<1, 64, 0, stream>>>(acc, out);
}

// Round 12
// 124.625 us; speedup vs baseline: 1.4240x; 1.4240x over previous
//
#include <hip/hip_runtime.h>
#include <cstdint>
#include <cstddef>

#define HW_N   262144       // 512*512 elements per (b,c) map
#define ROWS   128          // 32*4 maps
#define NCHUNK 512          // 512-elem chunks per row (one wave-shot each)

// fast log(1 + exp(-|z|)): arg of log in [1,2] -> v_exp + v_log, abs err ~1e-7
__device__ __forceinline__ float lg_term(float z) {
    return __logf(1.0f + __expf(-fabsf(z)));
}

__device__ __forceinline__ void block_reduce_add(double v, double* target, int tid) {
    #pragma unroll
    for (int o = 32; o > 0; o >>= 1) v += __shfl_down(v, o);
    __shared__ double sred[16];
    const int lane = tid & 63, wave = tid >> 6;
    if (lane == 0) sred[wave] = v;
    __syncthreads();
    if (tid == 0) {
        double s = 0.0;
        const int nw = blockDim.x >> 6;
        for (int w = 0; w < nw; ++w) s += sred[w];
        atomicAdd(target, s);
    }
}

// ---- pass 1: t -> bitmask + per-512-chunk positive counts ----
__global__ __launch_bounds__(1024) void count_kernel(
        const int4* __restrict__ t4, unsigned char* __restrict__ mask,
        int* __restrict__ chunkcnt) {
    const int blk = blockIdx.x;                 // 1024 blocks, 32768 elems each
    const size_t e0 = (size_t)blk * 32768;
    const int tid = threadIdx.x;
    const int lane = tid & 63, wave = tid >> 6; // 16 waves
    #pragma unroll
    for (int it = 0; it < 4; ++it) {
        const int j8 = it * 1024 + tid;         // 8-elem group within block
        const int4 a = t4[e0 / 4 + 2 * j8];
        const int4 b = t4[e0 / 4 + 2 * j8 + 1];
        const unsigned m =
            (unsigned)(a.x > 0)        | ((unsigned)(a.y > 0) << 1) |
            ((unsigned)(a.z > 0) << 2) | ((unsigned)(a.w > 0) << 3) |
            ((unsigned)(b.x > 0) << 4) | ((unsigned)(b.y > 0) << 5) |
            ((unsigned)(b.z > 0) << 6) | ((unsigned)(b.w > 0) << 7);
        mask[e0 / 8 + j8] = (unsigned char)m;
        int c = __popc(m);
        #pragma unroll
        for (int o = 32; o > 0; o >>= 1) c += __shfl_down(c, o);
        if (lane == 0) chunkcnt[blk * 64 + it * 16 + wave] = c;  // chunk = elem/512
    }
}

// ---- pass 2: per-row exclusive scan of 512 chunk counts -> chunkoff, k ----
__global__ __launch_bounds__(512) void offsets_kernel(
        const int* __restrict__ chunkcnt, int* __restrict__ chunkoff,
        int* __restrict__ kArr, double* __restrict__ acc) {
    const int row = blockIdx.x;
    const int tid = threadIdx.x;
    const int lane = tid & 63, wave = tid >> 6;   // 8 waves
    const int c = chunkcnt[row * NCHUNK + tid];
    int incl = c;
    #pragma unroll
    for (int o = 1; o < 64; o <<= 1) {
        const int u = __shfl_up(incl, o);
        if (lane >= o) incl += u;
    }
    __shared__ int wt[8];
    if (lane == 63) wt[wave] = incl;
    __syncthreads();
    int wpre = 0;
    #pragma unroll
    for (int w = 0; w < 8; ++w) wpre += (w < wave) ? wt[w] : 0;
    chunkoff[row * NCHUNK + tid] = wpre + incl - c;
    if (tid == NCHUNK - 1) {
        const int k = wpre + incl;
        kArr[row] = k < 1 ? 1 : k;      // true positive count (>=1 per reference)
    }
    if (blockIdx.x == 0 && tid < 2) acc[tid] = 0.0;
}

// ---- pass 3: fully fused CE + sim(A,B) loss. No pos array.
// Each positive (value v, global rank m) gathers its served elements j = m + i*k
// directly; (m,i) -> j is a bijection onto [0,N) so every A-term is covered once.
__global__ __launch_bounds__(256) void fused_kernel(
        const float4* __restrict__ x4, const unsigned char* __restrict__ mask,
        const int* __restrict__ chunkoff, const int* __restrict__ kArr,
        double* __restrict__ acc) {
    const int blk   = blockIdx.x;           // 4096 blocks, 16 chunks each
    const int row   = blk >> 5;             // 32 blocks/row
    const int bpart = blk & 31;
    const float*  xr  = (const float*)x4 + (size_t)row * HW_N;
    const float4* xr4 = x4 + (size_t)row * (HW_N / 4);
    const unsigned char* mr = mask + (size_t)row * (HW_N / 8);
    const int* cor = chunkoff + row * NCHUNK;
    const int k   = kArr[row];
    const int c0  = HW_N / k;               // base copy count (>=1)
    const int rem = HW_N - c0 * k;          // ranks m < rem get one extra copy

    const int tid  = threadIdx.x;
    const int lane = tid & 63;
    const int wave = tid >> 6;              // 0..3
    const unsigned long long below = (1ull << lane) - 1ull;

    double dtot = 0.0;                      // CE + A + B (equal weight, ALPHA=0.5)
    #pragma unroll
    for (int i = 0; i < 4; ++i) {
        const int rc = bpart * 16 + i * 4 + wave;   // row-chunk id (0..511)
        const int j0 = rc * 512 + lane * 8;          // element within row
        const float4 a = xr4[j0 / 4];
        const float4 b = xr4[j0 / 4 + 1];
        const unsigned mb = mr[j0 >> 3];
        int rank = 0;
        #pragma unroll
        for (int s = 0; s < 8; ++s) {
            const unsigned long long bs = __ballot((mb >> s) & 1);
            rank += __popcll(bs & below);
        }
        const int mbase = cor[rc] + rank;   // global rank of this lane's first positive

        const float v0 = a.x, v1 = a.y, v2 = a.z, v3 = a.w;
        const float v4 = b.x, v5 = b.y, v6 = b.z, v7 = b.w;
        float af = 0.0f;

        // CE: f(x,t) = (t ? max(-x,0) : max(x,0)) + log(1+exp(-|x|))
        #define CE(s, v) af += (((mb >> s) & 1) ? fmaxf(-(v), 0.0f) : fmaxf(v, 0.0f)) + lg_term(v);
        CE(0, v0) CE(1, v1) CE(2, v2) CE(3, v3)
        CE(4, v4) CE(5, v5) CE(6, v6) CE(7, v7)
        #undef CE

        // sim terms: per-bit rank is independent (popc of lower bits) -> ILP
        #define POS(s, v) if ((mb >> s) & 1) {                                        \
            const int m = mbase + __popc(mb & ((1u << s) - 1u));                      \
            for (int ii = 0; ii < c0; ++ii) {                                         \
                const int j2 = m + ii * k;                                            \
                const float dx = (v) * xr[j2];                                        \
                const int tt = (mr[j2 >> 3] >> (j2 & 7)) & 1;                         \
                af += (tt ? fmaxf(-dx, 0.0f) : fmaxf(dx, 0.0f)) + lg_term(dx);        \
            }                                                                         \
            if (m < rem) {                                                            \
                const int j2 = m + c0 * k;                                            \
                const float dx = (v) * xr[j2];                                        \
                const int tt = (mr[j2 >> 3] >> (j2 & 7)) & 1;                         \
                af += (tt ? fmaxf(-dx, 0.0f) : fmaxf(dx, 0.0f)) + lg_term(dx);        \
            }                                                                         \
            const float wgt = (float)c0 + ((m < rem) ? 1.0f : 0.0f);                  \
            af += wgt * (fmaxf(-(v), 0.0f) + lg_term(v));                             \
        }
        POS(0, v0) POS(1, v1) POS(2, v2) POS(3, v3)
        POS(4, v4) POS(5, v5) POS(6, v6) POS(7, v7)
        #undef POS

        dtot += (double)af;
    }
    block_reduce_add(dtot, &acc[0], tid);
}

__global__ void finalize_kernel(const double* __restrict__ acc, float* __restrict__ out) {
    if (threadIdx.x == 0 && blockIdx.x == 0) {
        const double inv = 1.0 / 33554432.0;    // 1 / (ROWS * HW_N)
        out[0] = (float)(0.5 * acc[0] * inv);   // ALPHA=0.5: equal weights, single sum
    }
}

extern "C" void kernel_launch(void* const* d_in, const int* in_sizes, int n_in,
                              void* d_out, int out_size, void* d_ws, size_t ws_size,
                              hipStream_t stream) {
    const float* x = (const float*)d_in[0];
    const int*   t = (const int*)d_in[1];
    float* out = (float*)d_out;

    // workspace layout (<= 13 MB now):
    //   [0,16)           f64 accumulator(s)
    //   [16384,16896)    kArr      (ROWS ints)
    //   [32768, +4MB)    mask      (ROWS*HW_N/8 bytes)
    //   [8MB, +256KB)    chunkcnt  (ROWS*NCHUNK ints)
    //   [12MB, +256KB)   chunkoff  (ROWS*NCHUNK ints)
    double*        acc      = (double*)d_ws;
    int*           kArr     = (int*)((char*)d_ws + 16384);
    unsigned char* mask     = (unsigned char*)d_ws + 32768;
    int*           chunkcnt = (int*)((char*)d_ws + (8u << 20));
    int*           chunkoff = (int*)((char*)d_ws + (12u << 20));

    count_kernel   <<<1024, 1024, 0, stream>>>((const int4*)t, mask, chunkcnt);
    offsets_kernel <<<ROWS, 512, 0, stream>>>(chunkcnt, chunkoff, kArr, acc);
    fused_kernel   <<<ROWS * 32, 256, 0, stream>>>((const float4*)x, mask, chunkoff, kArr, acc);
    finalize_kernel<<<1, 64, 0, stream>>>(acc, out);
}

// Round 13
// 112.090 us; speedup vs baseline: 1.5832x; 1.1118x over previous
//
#include <hip/hip_runtime.h>
#include <cstdint>
#include <cstddef>

#define HW_N   262144       // 512*512 elements per (b,c) map
#define ROWS   128          // 32*4 maps
#define NCHUNK 512          // 512-elem chunks per row (one wave-shot each)

__device__ __forceinline__ void block_reduce_add(double v, double* target, int tid) {
    #pragma unroll
    for (int o = 32; o > 0; o >>= 1) v += __shfl_down(v, o);
    __shared__ double sred[16];
    const int lane = tid & 63, wave = tid >> 6;
    if (lane == 0) sred[wave] = v;
    __syncthreads();
    if (tid == 0) {
        double s = 0.0;
        const int nw = blockDim.x >> 6;
        for (int w = 0; w < nw; ++w) s += sred[w];
        atomicAdd(target, s);
    }
}

// ---- pass 1: t -> bitmask + per-512-chunk positive counts ----
__global__ __launch_bounds__(1024) void count_kernel(
        const int4* __restrict__ t4, unsigned char* __restrict__ mask,
        int* __restrict__ chunkcnt) {
    const int blk = blockIdx.x;                 // 1024 blocks, 32768 elems each
    const size_t e0 = (size_t)blk * 32768;
    const int tid = threadIdx.x;
    const int lane = tid & 63, wave = tid >> 6; // 16 waves
    #pragma unroll
    for (int it = 0; it < 4; ++it) {
        const int j8 = it * 1024 + tid;         // 8-elem group within block
        const int4 a = t4[e0 / 4 + 2 * j8];
        const int4 b = t4[e0 / 4 + 2 * j8 + 1];
        const unsigned m =
            (unsigned)(a.x > 0)        | ((unsigned)(a.y > 0) << 1) |
            ((unsigned)(a.z > 0) << 2) | ((unsigned)(a.w > 0) << 3) |
            ((unsigned)(b.x > 0) << 4) | ((unsigned)(b.y > 0) << 5) |
            ((unsigned)(b.z > 0) << 6) | ((unsigned)(b.w > 0) << 7);
        mask[e0 / 8 + j8] = (unsigned char)m;
        int c = __popc(m);
        #pragma unroll
        for (int o = 32; o > 0; o >>= 1) c += __shfl_down(c, o);
        if (lane == 0) chunkcnt[blk * 64 + it * 16 + wave] = c;  // chunk = elem/512
    }
}

// ---- pass 2: per-row exclusive scan of 512 chunk counts -> chunkoff, k ----
__global__ __launch_bounds__(512) void offsets_kernel(
        const int* __restrict__ chunkcnt, int* __restrict__ chunkoff,
        int* __restrict__ kArr, double* __restrict__ acc) {
    const int row = blockIdx.x;
    const int tid = threadIdx.x;
    const int lane = tid & 63, wave = tid >> 6;   // 8 waves
    const int c = chunkcnt[row * NCHUNK + tid];
    int incl = c;
    #pragma unroll
    for (int o = 1; o < 64; o <<= 1) {
        const int u = __shfl_up(incl, o);
        if (lane >= o) incl += u;
    }
    __shared__ int wt[8];
    if (lane == 63) wt[wave] = incl;
    __syncthreads();
    int wpre = 0;
    #pragma unroll
    for (int w = 0; w < 8; ++w) wpre += (w < wave) ? wt[w] : 0;
    chunkoff[row * NCHUNK + tid] = wpre + incl - c;
    if (tid == NCHUNK - 1) {
        const int k = wpre + incl;
        kArr[row] = k < 1 ? 1 : k;      // true positive count (>=1 per reference)
    }
    if (blockIdx.x == 0 && tid < 2) acc[tid] = 0.0;
}

// ---- pass 3: fused CE + sim(A,B). Wave-local LDS compaction -> dense rounds.
// Positive rank m serves elements j = m + i*k, i < copies(m); (m,i)->j bijects [0,N).
// f(z,t) = max(z,0) - z*t + log(1+exp(-|z|)); logs batched via products.
__global__ __launch_bounds__(256) void fused_kernel(
        const float4* __restrict__ x4, const unsigned char* __restrict__ mask,
        const int* __restrict__ chunkoff, const int* __restrict__ kArr,
        double* __restrict__ acc) {
    const int blk   = blockIdx.x;           // 4096 blocks, 16 chunks each
    const int row   = blk >> 5;             // 32 blocks/row
    const int bpart = blk & 31;
    const float*  xr  = (const float*)x4 + (size_t)row * HW_N;
    const float4* xr4 = x4 + (size_t)row * (HW_N / 4);
    const unsigned char* mr = mask + (size_t)row * (HW_N / 8);
    const int* cor = chunkoff + row * NCHUNK;
    const int k   = kArr[row];
    const int c0  = HW_N / k;               // base copy count (>=1)
    const int rem = HW_N - c0 * k;          // ranks m < rem get one extra copy

    const int tid  = threadIdx.x;
    const int lane = tid & 63;
    const int wave = tid >> 6;              // 0..3

    __shared__ float lbuf[4][512];          // per-wave private compaction buffer
    float* wb = lbuf[wave];

    double dtot = 0.0;                      // CE + A + B (equal weight, ALPHA=0.5)
    #pragma unroll
    for (int i = 0; i < 4; ++i) {
        const int rc = bpart * 16 + i * 4 + wave;   // row-chunk id (0..511)
        const int j0 = rc * 512 + lane * 8;          // element within row
        const float4 a = xr4[j0 / 4];
        const float4 b = xr4[j0 / 4 + 1];
        const unsigned mb = mr[j0 >> 3];

        // ---- CE on owned elements: max(v,0) - v*t, logs batched into one ----
        float af = 0.0f;
        float prod = 1.0f;
        #define CE(s, v) { \
            af += fmaxf(v, 0.0f) - (((mb >> s) & 1) ? (v) : 0.0f); \
            prod *= 1.0f + __expf(-fabsf(v)); }
        CE(0, a.x) CE(1, a.y) CE(2, a.z) CE(3, a.w)
        CE(4, b.x) CE(5, b.y) CE(6, b.z) CE(7, b.w)
        #undef CE
        af += __logf(prod);                 // prod in [1,256] -> safe

        // ---- exclusive scan of per-lane popcounts -> slot base ----
        const int cnt = __popc(mb);
        int incl = cnt;
        #pragma unroll
        for (int o = 1; o < 64; o <<= 1) {
            const int u = __shfl_up(incl, o);
            if (lane >= o) incl += u;
        }
        const int base  = incl - cnt;
        const int total = __shfl(incl, 63);

        // ---- compact positive values into wave-private LDS ----
        {
            int r = base;
            #define ST(s, v) if ((mb >> s) & 1) { wb[r] = v; ++r; }
            ST(0, a.x) ST(1, a.y) ST(2, a.z) ST(3, a.w)
            ST(4, b.x) ST(5, b.y) ST(6, b.z) ST(7, b.w)
            #undef ST
        }
        // same-wave LDS read-after-write: compiler inserts lgkmcnt wait

        // ---- dense rounds: every lane processes one positive ----
        const int cbase = cor[rc];
        for (int p = lane; p < total; p += 64) {
            const float v = wb[p];
            const int m = cbase + p;
            const int copies = c0 + ((m < rem) ? 1 : 0);
            // B term: copies * f(v, 1)
            af += (float)copies * (fmaxf(-v, 0.0f) + __logf(1.0f + __expf(-fabsf(v))));
            // A terms over served elements j = m + i*k
            float prodA = 1.0f;
            int j = m;
            for (int ii = 0; ii < copies; ++ii) {
                const float xj = xr[j];
                const float dx = v * xj;
                const int tt = (mr[j >> 3] >> (j & 7)) & 1;
                af += fmaxf(dx, 0.0f) - (tt ? dx : 0.0f);
                prodA *= 1.0f + __expf(-fabsf(dx));
                j += k;
            }
            af += __logf(prodA);            // prodA in [1,8]
        }
        dtot += (double)af;
    }
    block_reduce_add(dtot, &acc[0], tid);
}

__global__ void finalize_kernel(const double* __restrict__ acc, float* __restrict__ out) {
    if (threadIdx.x == 0 && blockIdx.x == 0) {
        const double inv = 1.0 / 33554432.0;    // 1 / (ROWS * HW_N)
        out[0] = (float)(0.5 * acc[0] * inv);   // ALPHA=0.5: equal weights, single sum
    }
}

extern "C" void kernel_launch(void* const* d_in, const int* in_sizes, int n_in,
                              void* d_out, int out_size, void* d_ws, size_t ws_size,
                              hipStream_t stream) {
    const float* x = (const float*)d_in[0];
    const int*   t = (const int*)d_in[1];
    float* out = (float*)d_out;

    // workspace layout (<= 13 MB):
    //   [0,16)           f64 accumulator(s)
    //   [16384,16896)    kArr      (ROWS ints)
    //   [32768, +4MB)    mask      (ROWS*HW_N/8 bytes)
    //   [8MB, +256KB)    chunkcnt  (ROWS*NCHUNK ints)
    //   [12MB, +256KB)   chunkoff  (ROWS*NCHUNK ints)
    double*        acc      = (double*)d_ws;
    int*           kArr     = (int*)((char*)d_ws + 16384);
    unsigned char* mask     = (unsigned char*)d_ws + 32768;
    int*           chunkcnt = (int*)((char*)d_ws + (8u << 20));
    int*           chunkoff = (int*)((char*)d_ws + (12u << 20));

    count_kernel   <<<1024, 1024, 0, stream>>>((const int4*)t, mask, chunkcnt);
    offsets_kernel <<<ROWS, 512, 0, stream>>>(chunkcnt, chunkoff, kArr, acc);
    fused_kernel   <<<ROWS * 32, 256, 0, stream>>>((const float4*)x, mask, chunkoff, kArr, acc);
    finalize_kernel<<<1, 64, 0, stream>>>(acc, out);
}

// Round 14
// 91.921 us; speedup vs baseline: 1.9306x; 1.2194x over previous
//
#include <hip/hip_runtime.h>
#include <cstdint>
#include <cstddef>

#define HW_N   262144       // 512*512 elements per (b,c) map
#define ROWS   128          // 32*4 maps
#define NCHUNK 256          // 1024-elem chunks per row (one wave-shot each: 64 lanes x 16)

__device__ __forceinline__ void block_reduce_add(double v, double* target, int tid) {
    #pragma unroll
    for (int o = 32; o > 0; o >>= 1) v += __shfl_down(v, o);
    __shared__ double sred[16];
    const int lane = tid & 63, wave = tid >> 6;
    if (lane == 0) sred[wave] = v;
    __syncthreads();
    if (tid == 0) {
        double s = 0.0;
        const int nw = blockDim.x >> 6;
        for (int w = 0; w < nw; ++w) s += sred[w];
        atomicAdd(target, s);
    }
}

// ---- pass 1: t -> 16-bit masks + per-1024-chunk positive counts ----
__global__ __launch_bounds__(1024) void count_kernel(
        const int4* __restrict__ t4, unsigned short* __restrict__ mask16,
        int* __restrict__ chunkcnt) {
    const int blk = blockIdx.x;                 // 1024 blocks, 32768 elems each
    const size_t e0 = (size_t)blk * 32768;
    const int tid = threadIdx.x;
    const int lane = tid & 63, wave = tid >> 6; // 16 waves; wave's 64x16 = one chunk
    #pragma unroll
    for (int it = 0; it < 2; ++it) {
        const int g = it * 1024 + tid;          // 16-elem group index within block
        const size_t b4 = e0 / 4 + 4 * (size_t)g;
        const int4 a = t4[b4], b = t4[b4 + 1], c = t4[b4 + 2], d = t4[b4 + 3];
        const unsigned m =
            (unsigned)(a.x > 0)         | ((unsigned)(a.y > 0) << 1)  |
            ((unsigned)(a.z > 0) << 2)  | ((unsigned)(a.w > 0) << 3)  |
            ((unsigned)(b.x > 0) << 4)  | ((unsigned)(b.y > 0) << 5)  |
            ((unsigned)(b.z > 0) << 6)  | ((unsigned)(b.w > 0) << 7)  |
            ((unsigned)(c.x > 0) << 8)  | ((unsigned)(c.y > 0) << 9)  |
            ((unsigned)(c.z > 0) << 10) | ((unsigned)(c.w > 0) << 11) |
            ((unsigned)(d.x > 0) << 12) | ((unsigned)(d.y > 0) << 13) |
            ((unsigned)(d.z > 0) << 14) | ((unsigned)(d.w > 0) << 15);
        mask16[e0 / 16 + g] = (unsigned short)m;
        int cnt = __popc(m);
        #pragma unroll
        for (int o = 32; o > 0; o >>= 1) cnt += __shfl_down(cnt, o);
        if (lane == 0) chunkcnt[blk * 32 + it * 16 + wave] = cnt;
    }
}

// ---- pass 2: per-row exclusive scan of 256 chunk counts -> chunkoff, k ----
__global__ __launch_bounds__(256) void offsets_kernel(
        const int* __restrict__ chunkcnt, int* __restrict__ chunkoff,
        int* __restrict__ kArr, double* __restrict__ acc) {
    const int row = blockIdx.x;
    const int tid = threadIdx.x;
    const int lane = tid & 63, wave = tid >> 6;   // 4 waves
    const int c = chunkcnt[row * NCHUNK + tid];
    int incl = c;
    #pragma unroll
    for (int o = 1; o < 64; o <<= 1) {
        const int u = __shfl_up(incl, o);
        if (lane >= o) incl += u;
    }
    __shared__ int wt[4];
    if (lane == 63) wt[wave] = incl;
    __syncthreads();
    int wpre = 0;
    #pragma unroll
    for (int w = 0; w < 4; ++w) wpre += (w < wave) ? wt[w] : 0;
    chunkoff[row * NCHUNK + tid] = wpre + incl - c;
    if (tid == NCHUNK - 1) {
        const int k = wpre + incl;
        kArr[row] = k < 1 ? 1 : k;      // true positive count (>=1 per reference)
    }
    if (blockIdx.x == 0 && tid < 2) acc[tid] = 0.0;
}

// ---- pass 3: fused CE + sim(A,B). 1024-chunks, LDS densify, c0-specialized rounds.
// Positive rank m serves j = m + i*k, i < copies(m) = c0 + (m<rem); bijects [0,N).
// All logs batched: one log per 16 CE elems, one log per positive.
__global__ __launch_bounds__(256) void fused_kernel(
        const float4* __restrict__ x4, const unsigned short* __restrict__ mask16,
        const int* __restrict__ chunkoff, const int* __restrict__ kArr,
        double* __restrict__ acc) {
    const int blk   = blockIdx.x;           // 2048 blocks, 16 chunks each
    const int row   = blk >> 4;             // 16 blocks/row
    const int bpart = blk & 15;
    const float*  xr  = (const float*)x4 + (size_t)row * HW_N;
    const float4* xr4 = x4 + (size_t)row * (HW_N / 4);
    const unsigned char* mr8 = (const unsigned char*)(mask16 + (size_t)row * (HW_N / 16));
    const unsigned short* mr16 = mask16 + (size_t)row * (HW_N / 16);
    const int* cor = chunkoff + row * NCHUNK;
    const int k   = kArr[row];
    const int c0  = HW_N / k;               // base copy count (>=1), row-uniform
    const int rem = HW_N - c0 * k;          // ranks m < rem get one extra copy

    const int tid  = threadIdx.x;
    const int lane = tid & 63;
    const int wave = tid >> 6;              // 0..3

    __shared__ float lbuf[4][1024];         // per-wave private compaction buffer (16 KB)
    float* wb = lbuf[wave];

    double dtot = 0.0;                      // CE + A + B (equal weight, ALPHA=0.5)
    #pragma unroll
    for (int i = 0; i < 4; ++i) {
        const int rc = bpart * 16 + i * 4 + wave;   // row-chunk id (0..255)
        const int j0 = rc * 1024 + lane * 16;        // element within row
        const float4 a  = xr4[j0 / 4],     b  = xr4[j0 / 4 + 1];
        const float4 cc = xr4[j0 / 4 + 2], dd = xr4[j0 / 4 + 3];
        const unsigned mb = mr16[j0 >> 4];

        // ---- CE on 16 owned elements, single batched log ----
        float af = 0.0f;
        float prod = 1.0f;
        #define CE(s, v) { \
            af += fmaxf(v, 0.0f) - (((mb >> s) & 1) ? (v) : 0.0f); \
            prod *= 1.0f + __expf(-fabsf(v)); }
        CE(0, a.x)  CE(1, a.y)  CE(2, a.z)  CE(3, a.w)
        CE(4, b.x)  CE(5, b.y)  CE(6, b.z)  CE(7, b.w)
        CE(8, cc.x) CE(9, cc.y) CE(10, cc.z) CE(11, cc.w)
        CE(12, dd.x) CE(13, dd.y) CE(14, dd.z) CE(15, dd.w)
        #undef CE
        af += __logf(prod);                 // prod in [1, 65536] -> fine

        // ---- exclusive scan of per-lane popcounts -> slot base ----
        const int cnt = __popc(mb);
        int incl = cnt;
        #pragma unroll
        for (int o = 1; o < 64; o <<= 1) {
            const int u = __shfl_up(incl, o);
            if (lane >= o) incl += u;
        }
        const int base  = incl - cnt;
        const int total = __shfl(incl, 63);

        // ---- compact positive values into wave-private LDS ----
        {
            int r = base;
            #define ST(s, v) if ((mb >> s) & 1) { wb[r] = v; ++r; }
            ST(0, a.x)  ST(1, a.y)  ST(2, a.z)  ST(3, a.w)
            ST(4, b.x)  ST(5, b.y)  ST(6, b.z)  ST(7, b.w)
            ST(8, cc.x) ST(9, cc.y) ST(10, cc.z) ST(11, cc.w)
            ST(12, dd.x) ST(13, dd.y) ST(14, dd.z) ST(15, dd.w)
            #undef ST
        }

        // ---- dense rounds, specialized on row-uniform c0 ----
        const int cbase = cor[rc];
        if (c0 == 2) {
            for (int p = lane; p < total; p += 64) {
                const float v = wb[p];
                const int m = cbase + p;
                const float eB = 1.0f + __expf(-fabsf(v));
                const float nB = fmaxf(-v, 0.0f);
                float pr = eB * eB;
                float s = 2.0f * nB;
                {   const float dx = v * xr[m];
                    const int tt = (mr8[m >> 3] >> (m & 7)) & 1;
                    s += fmaxf(dx, 0.0f) - (tt ? dx : 0.0f);
                    pr *= 1.0f + __expf(-fabsf(dx)); }
                {   const int j = m + k;
                    const float dx = v * xr[j];
                    const int tt = (mr8[j >> 3] >> (j & 7)) & 1;
                    s += fmaxf(dx, 0.0f) - (tt ? dx : 0.0f);
                    pr *= 1.0f + __expf(-fabsf(dx)); }
                if (m < rem) {              // coherent: m consecutive within round
                    const int j = m + 2 * k;
                    const float dx = v * xr[j];
                    const int tt = (mr8[j >> 3] >> (j & 7)) & 1;
                    s += fmaxf(dx, 0.0f) - (tt ? dx : 0.0f) + nB;
                    pr *= (1.0f + __expf(-fabsf(dx))) * eB;
                }
                af += s + __logf(pr);       // pr <= 2^6
            }
        } else if (c0 == 1) {
            for (int p = lane; p < total; p += 64) {
                const float v = wb[p];
                const int m = cbase + p;
                const float eB = 1.0f + __expf(-fabsf(v));
                const float nB = fmaxf(-v, 0.0f);
                float pr = eB;
                float s = nB;
                {   const float dx = v * xr[m];
                    const int tt = (mr8[m >> 3] >> (m & 7)) & 1;
                    s += fmaxf(dx, 0.0f) - (tt ? dx : 0.0f);
                    pr *= 1.0f + __expf(-fabsf(dx)); }
                if (m < rem) {
                    const int j = m + k;
                    const float dx = v * xr[j];
                    const int tt = (mr8[j >> 3] >> (j & 7)) & 1;
                    s += fmaxf(dx, 0.0f) - (tt ? dx : 0.0f) + nB;
                    pr *= (1.0f + __expf(-fabsf(dx))) * eB;
                }
                af += s + __logf(pr);
            }
        } else {
            // generic fallback (not hit for this data)
            for (int p = lane; p < total; p += 64) {
                const float v = wb[p];
                const int m = cbase + p;
                const int copies = c0 + ((m < rem) ? 1 : 0);
                const float eB = 1.0f + __expf(-fabsf(v));
                float s = (float)copies * fmaxf(-v, 0.0f)
                        + (float)copies * __logf(eB);
                int j = m;
                float pr = 1.0f;
                for (int ii = 0; ii < copies; ++ii) {
                    const float dx = v * xr[j];
                    const int tt = (mr8[j >> 3] >> (j & 7)) & 1;
                    s += fmaxf(dx, 0.0f) - (tt ? dx : 0.0f);
                    pr *= 1.0f + __expf(-fabsf(dx));
                    j += k;
                }
                af += s + __logf(pr);
            }
        }
        dtot += (double)af;
    }
    block_reduce_add(dtot, &acc[0], tid);
}

__global__ void finalize_kernel(const double* __restrict__ acc, float* __restrict__ out) {
    if (threadIdx.x == 0 && blockIdx.x == 0) {
        const double inv = 1.0 / 33554432.0;    // 1 / (ROWS * HW_N)
        out[0] = (float)(0.5 * acc[0] * inv);   // ALPHA=0.5: equal weights, single sum
    }
}

extern "C" void kernel_launch(void* const* d_in, const int* in_sizes, int n_in,
                              void* d_out, int out_size, void* d_ws, size_t ws_size,
                              hipStream_t stream) {
    const float* x = (const float*)d_in[0];
    const int*   t = (const int*)d_in[1];
    float* out = (float*)d_out;

    // workspace layout (<= 13 MB):
    //   [0,16)           f64 accumulator(s)
    //   [16384,16896)    kArr      (ROWS ints)
    //   [32768, +4MB)    mask16    (ROWS*HW_N/16 ushorts)
    //   [8MB, +128KB)    chunkcnt  (ROWS*NCHUNK ints)
    //   [12MB, +128KB)   chunkoff  (ROWS*NCHUNK ints)
    double*         acc      = (double*)d_ws;
    int*            kArr     = (int*)((char*)d_ws + 16384);
    unsigned short* mask16   = (unsigned short*)((char*)d_ws + 32768);
    int*            chunkcnt = (int*)((char*)d_ws + (8u << 20));
    int*            chunkoff = (int*)((char*)d_ws + (12u << 20));

    count_kernel   <<<1024, 1024, 0, stream>>>((const int4*)t, mask16, chunkcnt);
    offsets_kernel <<<ROWS, 256, 0, stream>>>(chunkcnt, chunkoff, kArr, acc);
    fused_kernel   <<<ROWS * 16, 256, 0, stream>>>((const float4*)x, mask16, chunkoff, kArr, acc);
    finalize_kernel<<<1, 64, 0, stream>>>(acc, out);
}